// Round 14
// baseline (115.066 us; speedup 1.0000x reference)
//
#include <hip/hip_runtime.h>
#include <hip/hip_bf16.h>

constexpr int Sdim = 256;
constexpr int Cdim = 128;
constexpr int CRdim = 32;
constexpr int Bdim = 2;
constexpr int SS = Sdim * Sdim;      // 65536
constexpr int NPOS = Bdim * SS;      // 131072

typedef __attribute__((ext_vector_type(8))) short short8v;
typedef __attribute__((ext_vector_type(8))) unsigned short ushort8v;
typedef __attribute__((ext_vector_type(4))) float float4v;

__device__ __forceinline__ float bf2f(unsigned short v) {
    union { unsigned u; float f; } t; t.u = ((unsigned)v) << 16; return t.f;
}
__device__ __forceinline__ unsigned short f2bf(float f) {
    unsigned u = __float_as_uint(f);
    return (unsigned short)((u + 0x7fffu + ((u >> 16) & 1u)) >> 16);
}
__device__ __forceinline__ unsigned lds_addr_of(const void* p) {
    return (unsigned)(uintptr_t)(__attribute__((address_space(3))) const void*)p;
}

// ---------------- K0: weight prep ----------------
// pi(g,i) = g*4+i (i<4) else 16+g*4+(i-4) -- matches tr_read order (verified r5).
// NEW: u/lam weights composed with w_reduce (u = (Wu.Wred).x + (Wu.b_red+b_u)),
// same trick already verified for pre since round 5. K=128 for all GEMMs.
__global__ void k_prep(const float* __restrict__ w_reduce,
                       const float* __restrict__ w_u, const float* __restrict__ w_lam,
                       const float* __restrict__ w_w,
                       const float* __restrict__ b_red, const float* __restrict__ b_u,
                       const float* __restrict__ b_lam, const float* __restrict__ b_w,
                       const float* __restrict__ w_merge,
                       unsigned short* __restrict__ wm_frag,
                       unsigned short* __restrict__ wpreA,
                       unsigned short* __restrict__ wuA2, unsigned short* __restrict__ wlamA2,
                       float* __restrict__ biasPre,
                       float* __restrict__ buFrag, float* __restrict__ blamFrag)
{
    int t = blockIdx.x * 256 + threadIdx.x;   // 0..16383
    #pragma unroll
    for (int rep = 0; rep < 2; ++rep) {
        int f = t + rep * 16384;              // 0..32767
        int fi = f & 7, fl = (f >> 3) & 63, mt = (f >> 9) & 7, ks = (f >> 12) & 7;
        int fg = fl >> 4;
        int fk = (fi < 4) ? (fg * 4 + fi) : (16 + fg * 4 + (fi - 4));
        int cc = ks * 32 + fk;
        int co = mt * 16 + (fl & 15);
        float v;
        if (cc < 128) v = w_merge[co * 512 + cc]       + w_merge[co * 512 + cc + 128];
        else          v = w_merge[co * 512 + cc + 128] + w_merge[co * 512 + cc + 256];
        wm_frag[f] = f2bf(v);
    }

    int i = t & 7, lane = (t >> 3) & 63;
    int g = lane >> 4;
    int kk = (i < 4) ? (g * 4 + i) : (16 + g * 4 + (i - 4));

    // composed u/lam A-frags: [mt(8)][ks(4)][lane][i], K=128 over channel c
    {
        int fr = t >> 9;                      // 0..31
        int ks = fr & 3, mt = fr >> 2;
        int k = ks * 32 + kk;                 // channel c
        int co = mt * 16 + (lane & 15);
        float su = 0.f, sl = 0.f;
        for (int cr = 0; cr < 32; ++cr) {
            float wr = w_reduce[cr * 128 + k];
            su += w_u[co * 32 + cr] * wr;
            sl += w_lam[co * 32 + cr] * wr;
        }
        wuA2[t]   = f2bf(su);
        wlamA2[t] = f2bf(sl);
    }
    if (t < 2048) {   // pre A-frags: [ks(4)][lane][i], rows 0..2 valid
        int ks = t >> 9;
        int k = ks * 32 + kk;
        int row = lane & 15;
        float v = 0.f;
        if (row < 3)
            for (int cr = 0; cr < 32; ++cr) v += w_w[row * 32 + cr] * w_reduce[cr * 128 + k];
        wpreA[t] = f2bf(v);
    }
    if (t < 256) {    // composed pre bias, D-frag layout
        int r = t & 3, ln = t >> 2;
        int row = ((ln >> 4) << 2) + r;
        float v = 0.f;
        if (row < 3) {
            v = b_w[row];
            for (int cr = 0; cr < 32; ++cr) v += w_w[row * 32 + cr] * b_red[cr];
        }
        biasPre[t] = v;
    }
    if (t < 2048) {   // composed u/lam bias, D-frag layout [mt][lane][r]
        int r = t & 3, ln = (t >> 2) & 63, mt = t >> 8;
        int co = mt * 16 + ((ln >> 4) << 2) + r;
        float su = b_u[co], sl = b_lam[co];
        for (int cr = 0; cr < 32; ++cr) {
            su += w_u[co * 32 + cr] * b_red[cr];
            sl += w_lam[co * 32 + cr] * b_red[cr];
        }
        buFrag[t]   = su;
        blamFrag[t] = sl;
    }
}

// ---------------- K1: front end, single-barrier composed GEMMs ----------------
// stage x -> barrier -> 16 tr_reads into regs (reused by 3 GEMMs) ->
// pre GEMM (8 MFMA) + gains -> per-mt u/lam GEMM (16 MFMA) + immediate store.
// No red round-trip, no second barrier. LDS 32KB -> 5 blocks/CU.
__global__ __launch_bounds__(256, 4) void k_front(
    const float* __restrict__ x,
    const unsigned short* __restrict__ wpreA, const float* __restrict__ biasPre,
    const unsigned short* __restrict__ wuA2, const unsigned short* __restrict__ wlamA2,
    const float* __restrict__ buFrag, const float* __restrict__ blamFrag,
    unsigned short* __restrict__ u_o, unsigned short* __restrict__ v_o,
    float* __restrict__ Gv, float* __restrict__ Gh)
{
    __shared__ unsigned short lds[16384];   // 32KB X-tile only
    const int t   = threadIdx.x;
    const int p0  = blockIdx.x * 128;
    const int b   = p0 >> 16;
    const int hw0 = p0 & (SS - 1);

    // ---- stage: X-tile [pg(8)][cs(32)][4][16], linear conflict-free writes (r13)
    {
        #pragma unroll
        for (int pass = 0; pass < 8; ++pass) {
            int lin = pass * 2048 + t * 8;
            int pg  = lin >> 11;
            int rem = lin & 2047;
            int cs  = rem >> 6;
            int row = (rem >> 4) & 3;
            int col = rem & 15;
            int c   = cs * 4 + row;
            const float* src = x + (((size_t)(b * Cdim + c)) << 16) + hw0 + pg * 16 + col;
            float4 xa = *reinterpret_cast<const float4*>(src);
            float4 xb = *reinterpret_cast<const float4*>(src + 4);
            ushort8v val;
            val[0] = f2bf(xa.x); val[1] = f2bf(xa.y); val[2] = f2bf(xa.z); val[3] = f2bf(xa.w);
            val[4] = f2bf(xb.x); val[5] = f2bf(xb.y); val[6] = f2bf(xb.z); val[7] = f2bf(xb.w);
            *reinterpret_cast<ushort8v*>(&lds[lin]) = val;
        }
    }
    __syncthreads();

    const int lane = t & 63;
    const int wave = t >> 6;
    const int g    = lane >> 4;
    const unsigned vx = lds_addr_of(lds)
        + (unsigned)((wave << 13) + (g << 7) + ((lane & 15) << 3));

    // ---- x-fragments for this wave's 32 positions, all K=128 (16 tr_reads)
    short8v xf[4][2];
    #pragma unroll
    for (int ks = 0; ks < 4; ++ks) {
        unsigned ka = vx + (unsigned)(ks << 10);
        unsigned long long q00, q01, q10, q11;
        asm volatile(
            "ds_read_b64_tr_b16 %0, %4 offset:0\n\t"
            "ds_read_b64_tr_b16 %1, %4 offset:512\n\t"
            "ds_read_b64_tr_b16 %2, %4 offset:4096\n\t"
            "ds_read_b64_tr_b16 %3, %4 offset:4608\n\t"
            "s_waitcnt lgkmcnt(0)"
            : "=&v"(q00), "=&v"(q01), "=&v"(q10), "=&v"(q11)
            : "v"(ka));
        __builtin_amdgcn_sched_barrier(0);
        union { unsigned long long u[2]; short8v v; } f0, f1;
        f0.u[0] = q00; f0.u[1] = q01;
        f1.u[0] = q10; f1.u[1] = q11;
        xf[ks][0] = f0.v;
        xf[ks][1] = f1.v;
    }

    const float4v zz = (float4v){0.f, 0.f, 0.f, 0.f};

    // ---- pre GEMM (M=16, rows 0..2) + gains epilogue
    {
        const short8v* wp = reinterpret_cast<const short8v*>(wpreA);
        float4v p0 = zz, p1 = zz;
        #pragma unroll
        for (int ks = 0; ks < 4; ++ks) {
            short8v a = wp[(ks << 6) + lane];
            p0 = __builtin_amdgcn_mfma_f32_16x16x32_bf16(a, xf[ks][0], p0, 0, 0, 0);
            p1 = __builtin_amdgcn_mfma_f32_16x16x32_bf16(a, xf[ks][1], p1, 0, 0, 0);
        }
        float4 bp = *reinterpret_cast<const float4*>(biasPre + (lane << 2));
        if (lane < 16) {
            #pragma unroll
            for (int nt = 0; nt < 2; ++nt) {
                float4v pv = nt ? p1 : p0;
                float pr0 = pv[0] + bp.x;
                float pr1 = pv[1] + bp.y;
                float pr2 = pv[2] + bp.z;
                float s0 = 1.f / (1.f + expf(-pr0));
                float s1 = 1.f / (1.f + expf(-pr1));
                float s2 = 1.f / (1.f + expf(-pr2));
                float inv = 1.f / fmaxf(s0 + s1 + s2, 1e-6f);
                int hw = hw0 + wave * 32 + nt * 16 + lane;
                int hh = hw >> 8, wp2 = hw & 255;
                float ghv = (s1 + (hh >= 1 ? s0 : 0.f) + (hh <= Sdim - 2 ? s2 : 0.f)) * inv;
                float gvv = (s1 + (wp2 >= 1 ? s0 : 0.f) + (wp2 <= Sdim - 2 ? s2 : 0.f)) * inv;
                Gh[(b << 16) + hw] = ghv;
                Gv[(b << 16) + (wp2 << 8) + hh] = gvv;
            }
        }
    }

    // ---- composed u/lam GEMMs, per-mt epilogue (v = lam * x from LDS)
    const short8v* wu = reinterpret_cast<const short8v*>(wuA2);
    const short8v* wl = reinterpret_cast<const short8v*>(wlamA2);
    #pragma unroll
    for (int mt = 0; mt < 8; ++mt) {
        float4v au0 = zz, au1 = zz, al0 = zz, al1 = zz;
        #pragma unroll
        for (int ks = 0; ks < 4; ++ks) {
            short8v a_u = wu[(((mt << 2) + ks) << 6) + lane];
            short8v a_l = wl[(((mt << 2) + ks) << 6) + lane];
            au0 = __builtin_amdgcn_mfma_f32_16x16x32_bf16(a_u, xf[ks][0], au0, 0, 0, 0);
            au1 = __builtin_amdgcn_mfma_f32_16x16x32_bf16(a_u, xf[ks][1], au1, 0, 0, 0);
            al0 = __builtin_amdgcn_mfma_f32_16x16x32_bf16(a_l, xf[ks][0], al0, 0, 0, 0);
            al1 = __builtin_amdgcn_mfma_f32_16x16x32_bf16(a_l, xf[ks][1], al1, 0, 0, 0);
        }
        float4 bu = *reinterpret_cast<const float4*>(buFrag + ((mt * 64 + lane) << 2));
        float4 bl = *reinterpret_cast<const float4*>(blamFrag + ((mt * 64 + lane) << 2));
        #pragma unroll
        for (int nt = 0; nt < 2; ++nt) {
            float4v uu = nt ? au1 : au0;
            float4v ll = nt ? al1 : al0;
            int pp = wave * 32 + nt * 16 + (lane & 15);
            #pragma unroll
            for (int r = 0; r < 4; ++r) {
                int co = mt * 16 + g * 4 + r;
                int xoff = ((pp >> 4) << 11) + ((co >> 2) << 6) + ((co & 3) << 4) + (pp & 15);
                float xv = bf2f(lds[xoff]);
                float bur = (r == 0 ? bu.x : r == 1 ? bu.y : r == 2 ? bu.z : bu.w);
                float blr = (r == 0 ? bl.x : r == 1 ? bl.y : r == 2 ? bl.z : bl.w);
                size_t gidx = (((size_t)(b * Cdim + co)) << 16) + (size_t)(hw0 + pp);
                u_o[gidx] = f2bf(uu[r] + bur);
                v_o[gidx] = f2bf((ll[r] + blr) * xv);
            }
        }
    }
}

// ---------------- K2: 2-chunk scan with exact carry (round-8 proven form) ----------------
__global__ __launch_bounds__(512, 4) void k_scan_split(
    const unsigned short* __restrict__ u, const unsigned short* __restrict__ v,
    const float* __restrict__ Gv, const float* __restrict__ Gh,
    unsigned short* __restrict__ ov, unsigned short* __restrict__ oh)
{
    __shared__ float Hb[256];

    const int id   = blockIdx.x;
    const int j    = threadIdx.x & 255;
    const int half = threadIdx.x >> 8;    // wave-uniform
    const bool vert = (id < Bdim * Cdim);

    float L = 0.f, P = 1.f;

    if (vert) {
        int bc = id, b = bc >> 7;
        size_t base = (size_t)bc * SS + j;
        const float* Gb = Gv + (b << 16) + j;
        if (half == 0) {
            float h = 0.f;
            #pragma unroll 8
            for (int i = 0; i < 128; ++i) {
                size_t idx = base + ((size_t)i << 8);
                float g = Gb[i << 8];
                h = fmaf(h, g, bf2f(v[idx]));
                ov[idx] = f2bf(h * bf2f(u[idx]));
            }
            Hb[j] = h;
        } else {
            #pragma unroll 8
            for (int i = 128; i < 256; ++i) {
                float g = Gb[i << 8];
                L = fmaf(L, g, bf2f(v[base + ((size_t)i << 8)]));
                P *= g;
            }
        }
    } else {
        int bc = id - Bdim * Cdim, b = bc >> 7;
        size_t rbase = (size_t)bc * SS + (size_t)j * Sdim;
        const float* Gb = Gh + (b << 16) + j;
        if (half == 0) {
            size_t obase = (size_t)bc * SS + j;
            float h = 0.f;
            #pragma unroll
            for (int t8 = 0; t8 < 16; ++t8) {
                ushort8v v8 = *reinterpret_cast<const ushort8v*>(v + rbase + t8 * 8);
                ushort8v u8 = *reinterpret_cast<const ushort8v*>(u + rbase + t8 * 8);
                #pragma unroll
                for (int k = 0; k < 8; ++k) {
                    int i = t8 * 8 + k;
                    float g = Gb[i << 8];
                    h = fmaf(h, g, bf2f(v8[k]));
                    oh[obase + ((size_t)i << 8)] = f2bf(h * bf2f(u8[k]));
                }
            }
            Hb[j] = h;
        } else {
            #pragma unroll
            for (int t8 = 0; t8 < 16; ++t8) {
                ushort8v v8 = *reinterpret_cast<const ushort8v*>(v + rbase + 128 + t8 * 8);
                #pragma unroll
                for (int k = 0; k < 8; ++k) {
                    float g = Gb[(128 + t8 * 8 + k) << 8];
                    L = fmaf(L, g, bf2f(v8[k]));
                    P *= g;
                }
            }
        }
    }

    __syncthreads();

    if (half == 1) {
        float h0;
        if (vert) {
            int bc = id;
            size_t base = (size_t)bc * SS + j;
            const float* Gb = Gv + ((bc >> 7) << 16) + j;
            h0 = Hb[j];
            float Lr = 0.f, Pr = 1.f;
            #pragma unroll 8
            for (int i = 128; i < 256; ++i) {
                size_t idx = base + ((size_t)i << 8);
                float g = Gb[i << 8];
                Lr = fmaf(Lr, g, bf2f(v[idx]));     // L2-warm reread
                Pr *= g;
                float h = fmaf(h0, Pr, Lr);
                ov[idx] = f2bf(h * bf2f(u[idx]));
            }
        } else {
            int bc = id - Bdim * Cdim;
            size_t rbase = (size_t)bc * SS + (size_t)j * Sdim;
            size_t obase = (size_t)bc * SS + j;
            const float* Gb = Gh + ((bc >> 7) << 16) + j;
            h0 = Hb[j];
            float Lr = 0.f, Pr = 1.f;
            #pragma unroll
            for (int t8 = 0; t8 < 16; ++t8) {
                ushort8v v8 = *reinterpret_cast<const ushort8v*>(v + rbase + 128 + t8 * 8);
                ushort8v u8 = *reinterpret_cast<const ushort8v*>(u + rbase + 128 + t8 * 8);
                #pragma unroll
                for (int k = 0; k < 8; ++k) {
                    int i = 128 + t8 * 8 + k;
                    float g = Gb[i << 8];
                    Lr = fmaf(Lr, g, bf2f(v8[k]));
                    Pr *= g;
                    float h = fmaf(h0, Pr, Lr);
                    oh[obase + ((size_t)i << 8)] = f2bf(h * bf2f(u8[k]));
                }
            }
        }
        (void)h0; (void)L; (void)P;
    }
}

// ---------------- K3: merge via MFMA, 64-position tile (round-10/11, ~floor) ----------------
__global__ __launch_bounds__(256, 4) void k_merge_mfma(
    const unsigned short* __restrict__ ov, const unsigned short* __restrict__ oh,
    const unsigned short* __restrict__ wm_frag,
    const float* __restrict__ b_merge, float* __restrict__ out)
{
    __shared__ unsigned short lds[16384];   // 32 KB: 64 pos x 256 c
    const int t   = threadIdx.x;
    const int p0  = blockIdx.x * 64;
    const int b   = p0 >> 16;
    const int hw0 = p0 & (SS - 1);

    {
        const int w0 = (t & 7) * 8;
        #pragma unroll
        for (int pass = 0; pass < 8; ++pass) {
            int c = (t >> 3) + pass * 32;
            const unsigned short* src = (c < Cdim)
                ? ov + (((size_t)(b * Cdim + c)) << 16) + hw0 + w0
                : oh + (((size_t)(b * Cdim + (c - Cdim))) << 16) + hw0 + w0;
            ushort8v val = *reinterpret_cast<const ushort8v*>(src);
            int off = ((w0 >> 4) << 12) + ((c >> 2) << 6) + ((c & 3) << 4) + (w0 & 15);
            *reinterpret_cast<ushort8v*>(&lds[off]) = val;
        }
    }
    __syncthreads();

    const int lane = t & 63;
    const int wave = t >> 6;
    const unsigned v_addr = lds_addr_of(lds)
        + (unsigned)((wave << 13) + ((lane >> 4) << 7) + ((lane & 15) << 3));

    float4v acc[8];
    #pragma unroll
    for (int mt = 0; mt < 8; ++mt) acc[mt] = (float4v){0.f, 0.f, 0.f, 0.f};

    const short8v* wf = reinterpret_cast<const short8v*>(wm_frag);

    #pragma unroll 2
    for (int ks2 = 0; ks2 < 4; ++ks2) {
        int ksA = 2 * ks2, ksB = 2 * ks2 + 1;
        unsigned ka = v_addr + (unsigned)(ks2 << 11);
        unsigned long long b00, b01, b10, b11;
        asm volatile(
            "ds_read_b64_tr_b16 %0, %4 offset:0\n\t"
            "ds_read_b64_tr_b16 %1, %4 offset:512\n\t"
            "ds_read_b64_tr_b16 %2, %4 offset:1024\n\t"
            "ds_read_b64_tr_b16 %3, %4 offset:1536\n\t"
            "s_waitcnt lgkmcnt(0)"
            : "=&v"(b00), "=&v"(b01), "=&v"(b10), "=&v"(b11)
            : "v"(ka));
        __builtin_amdgcn_sched_barrier(0);

        union { unsigned long long u[2]; short8v v; } f0, f1;
        f0.u[0] = b00; f0.u[1] = b01;
        f1.u[0] = b10; f1.u[1] = b11;
        short8v bnA = f0.v;
        short8v bnB = f1.v;

        #pragma unroll
        for (int mt = 0; mt < 8; ++mt)
            acc[mt] = __builtin_amdgcn_mfma_f32_16x16x32_bf16(wf[((ksA << 3) + mt) * 64 + lane], bnA, acc[mt], 0, 0, 0);
        #pragma unroll
        for (int mt = 0; mt < 8; ++mt)
            acc[mt] = __builtin_amdgcn_mfma_f32_16x16x32_bf16(wf[((ksB << 3) + mt) * 64 + lane], bnB, acc[mt], 0, 0, 0);
    }

    const int pl = (wave << 4) + (lane & 15);
    const int r0 = (lane >> 4) << 2;
    #pragma unroll
    for (int mt = 0; mt < 8; ++mt) {
        size_t col = (size_t)hw0 + pl;
        #pragma unroll
        for (int r = 0; r < 4; ++r) {
            int co = (mt << 4) + r0 + r;
            out[(((size_t)(b * Cdim + co)) << 16) + col] = acc[mt][r] + b_merge[co];
        }
    }
}

extern "C" void kernel_launch(void* const* d_in, const int* in_sizes, int n_in,
                              void* d_out, int out_size, void* d_ws, size_t ws_size,
                              hipStream_t stream)
{
    const float* x        = (const float*)d_in[0];
    const float* w_reduce = (const float*)d_in[1];
    const float* b_red    = (const float*)d_in[2];
    const float* w_u      = (const float*)d_in[3];
    const float* b_u      = (const float*)d_in[4];
    const float* w_lam    = (const float*)d_in[5];
    const float* b_lam    = (const float*)d_in[6];
    const float* w_w      = (const float*)d_in[7];
    const float* b_w      = (const float*)d_in[8];
    const float* w_merge  = (const float*)d_in[11];
    const float* b_merge  = (const float*)d_in[12];
    float* out = (float*)d_out;

    char* ws = (char*)d_ws;
    unsigned short* u_buf = (unsigned short*)(ws);                 // 32 MiB bf16
    unsigned short* v_buf = (unsigned short*)(ws + 33554432);      // 32 MiB  (v = lam*x)
    unsigned short* ov    = (unsigned short*)(ws + 67108864);      // 32 MiB
    unsigned short* oh    = (unsigned short*)(ws + 100663296);     // 32 MiB
    float* Gv    = (float*)(ws + 134217728);                       // 512 KiB
    float* Gh    = (float*)(ws + 134742016);                       // 512 KiB
    unsigned short* wm_frag = (unsigned short*)(ws + 135282688);   // 64 KiB bf16

    // front-end frags in the (dead until scan) ov region
    unsigned short* wpreA  = (unsigned short*)(ws + 67108864);           // 4 KiB
    unsigned short* wuA2   = (unsigned short*)(ws + 67108864 + 4096);    // 32 KiB
    unsigned short* wlamA2 = (unsigned short*)(ws + 67108864 + 36864);   // 32 KiB
    float* biasPre         = (float*)(ws + 67108864 + 69632);            // 1 KiB
    float* buFrag          = (float*)(ws + 67108864 + 73728);            // 8 KiB
    float* blamFrag        = (float*)(ws + 67108864 + 81920);            // 8 KiB

    hipLaunchKernelGGL(k_prep, dim3(64), dim3(256), 0, stream,
                       w_reduce, w_u, w_lam, w_w, b_red, b_u, b_lam, b_w, w_merge,
                       wm_frag, wpreA, wuA2, wlamA2, biasPre, buFrag, blamFrag);
    hipLaunchKernelGGL(k_front, dim3(NPOS / 128), dim3(256), 0, stream,
                       x, wpreA, biasPre, wuA2, wlamA2, buFrag, blamFrag,
                       u_buf, v_buf, Gv, Gh);
    hipLaunchKernelGGL(k_scan_split, dim3(2 * Bdim * Cdim), dim3(512), 0, stream,
                       u_buf, v_buf, Gv, Gh, ov, oh);
    hipLaunchKernelGGL(k_merge_mfma, dim3(NPOS / 64), dim3(256), 0, stream,
                       ov, oh, wm_frag, b_merge, out);
}

// Round 15
// 108.125 us; speedup vs baseline: 1.0642x; 1.0642x over previous
//
#include <hip/hip_runtime.h>
#include <hip/hip_bf16.h>

constexpr int Sdim = 256;
constexpr int Cdim = 128;
constexpr int CRdim = 32;
constexpr int Bdim = 2;
constexpr int SS = Sdim * Sdim;      // 65536
constexpr int NPOS = Bdim * SS;      // 131072

typedef __attribute__((ext_vector_type(8))) short short8v;
typedef __attribute__((ext_vector_type(8))) unsigned short ushort8v;
typedef __attribute__((ext_vector_type(4))) float float4v;
typedef __attribute__((ext_vector_type(4))) unsigned int uint4v;

__device__ __forceinline__ float bf2f(unsigned short v) {
    union { unsigned u; float f; } t; t.u = ((unsigned)v) << 16; return t.f;
}
__device__ __forceinline__ unsigned short f2bf(float f) {
    unsigned u = __float_as_uint(f);
    return (unsigned short)((u + 0x7fffu + ((u >> 16) & 1u)) >> 16);
}
__device__ __forceinline__ unsigned lds_addr_of(const void* p) {
    return (unsigned)(uintptr_t)(__attribute__((address_space(3))) const void*)p;
}

// ---------------- K0: weight prep (round-14 composed form, verified) ----------------
__global__ void k_prep(const float* __restrict__ w_reduce,
                       const float* __restrict__ w_u, const float* __restrict__ w_lam,
                       const float* __restrict__ w_w,
                       const float* __restrict__ b_red, const float* __restrict__ b_u,
                       const float* __restrict__ b_lam, const float* __restrict__ b_w,
                       const float* __restrict__ w_merge,
                       unsigned short* __restrict__ wm_frag,
                       unsigned short* __restrict__ wpreA,
                       unsigned short* __restrict__ wuA2, unsigned short* __restrict__ wlamA2,
                       float* __restrict__ biasPre,
                       float* __restrict__ buFrag, float* __restrict__ blamFrag)
{
    int t = blockIdx.x * 256 + threadIdx.x;   // 0..16383
    #pragma unroll
    for (int rep = 0; rep < 2; ++rep) {
        int f = t + rep * 16384;              // 0..32767
        int fi = f & 7, fl = (f >> 3) & 63, mt = (f >> 9) & 7, ks = (f >> 12) & 7;
        int fg = fl >> 4;
        int fk = (fi < 4) ? (fg * 4 + fi) : (16 + fg * 4 + (fi - 4));
        int cc = ks * 32 + fk;
        int co = mt * 16 + (fl & 15);
        float v;
        if (cc < 128) v = w_merge[co * 512 + cc]       + w_merge[co * 512 + cc + 128];
        else          v = w_merge[co * 512 + cc + 128] + w_merge[co * 512 + cc + 256];
        wm_frag[f] = f2bf(v);
    }

    int i = t & 7, lane = (t >> 3) & 63;
    int g = lane >> 4;
    int kk = (i < 4) ? (g * 4 + i) : (16 + g * 4 + (i - 4));

    // composed u/lam A-frags: [mt(8)][ks(4)][lane][i], K=128 over channel c
    {
        int fr = t >> 9;                      // 0..31
        int ks = fr & 3, mt = fr >> 2;
        int k = ks * 32 + kk;
        int co = mt * 16 + (lane & 15);
        float su = 0.f, sl = 0.f;
        for (int cr = 0; cr < 32; ++cr) {
            float wr = w_reduce[cr * 128 + k];
            su += w_u[co * 32 + cr] * wr;
            sl += w_lam[co * 32 + cr] * wr;
        }
        wuA2[t]   = f2bf(su);
        wlamA2[t] = f2bf(sl);
    }
    if (t < 2048) {   // pre A-frags: [ks(4)][lane][i], rows 0..2 valid
        int ks = t >> 9;
        int k = ks * 32 + kk;
        int row = lane & 15;
        float v = 0.f;
        if (row < 3)
            for (int cr = 0; cr < 32; ++cr) v += w_w[row * 32 + cr] * w_reduce[cr * 128 + k];
        wpreA[t] = f2bf(v);
    }
    if (t < 256) {    // composed pre bias, D-frag layout
        int r = t & 3, ln = t >> 2;
        int row = ((ln >> 4) << 2) + r;
        float v = 0.f;
        if (row < 3) {
            v = b_w[row];
            for (int cr = 0; cr < 32; ++cr) v += w_w[row * 32 + cr] * b_red[cr];
        }
        biasPre[t] = v;
    }
    if (t < 2048) {   // composed u/lam bias, D-frag layout [mt][lane][r]
        int r = t & 3, ln = (t >> 2) & 63, mt = t >> 8;
        int co = mt * 16 + ((ln >> 4) << 2) + r;
        float su = b_u[co], sl = b_lam[co];
        for (int cr = 0; cr < 32; ++cr) {
            su += w_u[co * 32 + cr] * b_red[cr];
            sl += w_lam[co * 32 + cr] * b_red[cr];
        }
        buFrag[t]   = su;
        blamFrag[t] = sl;
    }
}

// ---------------- K1: front end, composed GEMMs + PACKED uv output ----------------
// Round-15: u,v packed into one uint32 (lo=u, hi=v) -> 64 dword stores/thread
// instead of 128 short stores. Everything else = round-14 (single barrier,
// composed K=128 GEMMs, 32KB LDS).
__global__ __launch_bounds__(256, 4) void k_front(
    const float* __restrict__ x,
    const unsigned short* __restrict__ wpreA, const float* __restrict__ biasPre,
    const unsigned short* __restrict__ wuA2, const unsigned short* __restrict__ wlamA2,
    const float* __restrict__ buFrag, const float* __restrict__ blamFrag,
    unsigned* __restrict__ uv_o,
    float* __restrict__ Gv, float* __restrict__ Gh)
{
    __shared__ unsigned short lds[16384];   // 32KB X-tile only
    const int t   = threadIdx.x;
    const int p0  = blockIdx.x * 128;
    const int b   = p0 >> 16;
    const int hw0 = p0 & (SS - 1);

    // ---- stage: X-tile [pg(8)][cs(32)][4][16], linear conflict-free writes (r13)
    {
        #pragma unroll
        for (int pass = 0; pass < 8; ++pass) {
            int lin = pass * 2048 + t * 8;
            int pg  = lin >> 11;
            int rem = lin & 2047;
            int cs  = rem >> 6;
            int row = (rem >> 4) & 3;
            int col = rem & 15;
            int c   = cs * 4 + row;
            const float* src = x + (((size_t)(b * Cdim + c)) << 16) + hw0 + pg * 16 + col;
            float4 xa = *reinterpret_cast<const float4*>(src);
            float4 xb = *reinterpret_cast<const float4*>(src + 4);
            ushort8v val;
            val[0] = f2bf(xa.x); val[1] = f2bf(xa.y); val[2] = f2bf(xa.z); val[3] = f2bf(xa.w);
            val[4] = f2bf(xb.x); val[5] = f2bf(xb.y); val[6] = f2bf(xb.z); val[7] = f2bf(xb.w);
            *reinterpret_cast<ushort8v*>(&lds[lin]) = val;
        }
    }
    __syncthreads();

    const int lane = t & 63;
    const int wave = t >> 6;
    const int g    = lane >> 4;
    const unsigned vx = lds_addr_of(lds)
        + (unsigned)((wave << 13) + (g << 7) + ((lane & 15) << 3));

    // ---- x-fragments for this wave's 32 positions (16 tr_reads, reused 3x)
    short8v xf[4][2];
    #pragma unroll
    for (int ks = 0; ks < 4; ++ks) {
        unsigned ka = vx + (unsigned)(ks << 10);
        unsigned long long q00, q01, q10, q11;
        asm volatile(
            "ds_read_b64_tr_b16 %0, %4 offset:0\n\t"
            "ds_read_b64_tr_b16 %1, %4 offset:512\n\t"
            "ds_read_b64_tr_b16 %2, %4 offset:4096\n\t"
            "ds_read_b64_tr_b16 %3, %4 offset:4608\n\t"
            "s_waitcnt lgkmcnt(0)"
            : "=&v"(q00), "=&v"(q01), "=&v"(q10), "=&v"(q11)
            : "v"(ka));
        __builtin_amdgcn_sched_barrier(0);
        union { unsigned long long u[2]; short8v v; } f0, f1;
        f0.u[0] = q00; f0.u[1] = q01;
        f1.u[0] = q10; f1.u[1] = q11;
        xf[ks][0] = f0.v;
        xf[ks][1] = f1.v;
    }

    const float4v zz = (float4v){0.f, 0.f, 0.f, 0.f};

    // ---- pre GEMM (M=16, rows 0..2) + gains epilogue
    {
        const short8v* wp = reinterpret_cast<const short8v*>(wpreA);
        float4v p0v = zz, p1v = zz;
        #pragma unroll
        for (int ks = 0; ks < 4; ++ks) {
            short8v a = wp[(ks << 6) + lane];
            p0v = __builtin_amdgcn_mfma_f32_16x16x32_bf16(a, xf[ks][0], p0v, 0, 0, 0);
            p1v = __builtin_amdgcn_mfma_f32_16x16x32_bf16(a, xf[ks][1], p1v, 0, 0, 0);
        }
        float4 bp = *reinterpret_cast<const float4*>(biasPre + (lane << 2));
        if (lane < 16) {
            #pragma unroll
            for (int nt = 0; nt < 2; ++nt) {
                float4v pv = nt ? p1v : p0v;
                float pr0 = pv[0] + bp.x;
                float pr1 = pv[1] + bp.y;
                float pr2 = pv[2] + bp.z;
                float s0 = 1.f / (1.f + expf(-pr0));
                float s1 = 1.f / (1.f + expf(-pr1));
                float s2 = 1.f / (1.f + expf(-pr2));
                float inv = 1.f / fmaxf(s0 + s1 + s2, 1e-6f);
                int hw = hw0 + wave * 32 + nt * 16 + lane;
                int hh = hw >> 8, wp2 = hw & 255;
                float ghv = (s1 + (hh >= 1 ? s0 : 0.f) + (hh <= Sdim - 2 ? s2 : 0.f)) * inv;
                float gvv = (s1 + (wp2 >= 1 ? s0 : 0.f) + (wp2 <= Sdim - 2 ? s2 : 0.f)) * inv;
                Gh[(b << 16) + hw] = ghv;
                Gv[(b << 16) + (wp2 << 8) + hh] = gvv;
            }
        }
    }

    // ---- composed u/lam GEMMs, per-mt epilogue, packed dword store
    const short8v* wu = reinterpret_cast<const short8v*>(wuA2);
    const short8v* wl = reinterpret_cast<const short8v*>(wlamA2);
    #pragma unroll
    for (int mt = 0; mt < 8; ++mt) {
        float4v au0 = zz, au1 = zz, al0 = zz, al1 = zz;
        #pragma unroll
        for (int ks = 0; ks < 4; ++ks) {
            short8v a_u = wu[(((mt << 2) + ks) << 6) + lane];
            short8v a_l = wl[(((mt << 2) + ks) << 6) + lane];
            au0 = __builtin_amdgcn_mfma_f32_16x16x32_bf16(a_u, xf[ks][0], au0, 0, 0, 0);
            au1 = __builtin_amdgcn_mfma_f32_16x16x32_bf16(a_u, xf[ks][1], au1, 0, 0, 0);
            al0 = __builtin_amdgcn_mfma_f32_16x16x32_bf16(a_l, xf[ks][0], al0, 0, 0, 0);
            al1 = __builtin_amdgcn_mfma_f32_16x16x32_bf16(a_l, xf[ks][1], al1, 0, 0, 0);
        }
        float4 bu = *reinterpret_cast<const float4*>(buFrag + ((mt * 64 + lane) << 2));
        float4 bl = *reinterpret_cast<const float4*>(blamFrag + ((mt * 64 + lane) << 2));
        #pragma unroll
        for (int nt = 0; nt < 2; ++nt) {
            float4v uu = nt ? au1 : au0;
            float4v ll = nt ? al1 : al0;
            int pp = wave * 32 + nt * 16 + (lane & 15);
            #pragma unroll
            for (int r = 0; r < 4; ++r) {
                int co = mt * 16 + g * 4 + r;
                int xoff = ((pp >> 4) << 11) + ((co >> 2) << 6) + ((co & 3) << 4) + (pp & 15);
                float xv = bf2f(lds[xoff]);
                float bur = (r == 0 ? bu.x : r == 1 ? bu.y : r == 2 ? bu.z : bu.w);
                float blr = (r == 0 ? bl.x : r == 1 ? bl.y : r == 2 ? bl.z : bl.w);
                size_t gidx = (((size_t)(b * Cdim + co)) << 16) + (size_t)(hw0 + pp);
                unsigned pk = (unsigned)f2bf(uu[r] + bur)
                            | ((unsigned)f2bf((ll[r] + blr) * xv) << 16);
                uv_o[gidx] = pk;
            }
        }
    }
}

// ---------------- K2: 2-chunk scan, packed-uv input (round-8 structure) ----------------
__global__ __launch_bounds__(512, 4) void k_scan_split(
    const unsigned* __restrict__ uv,
    const float* __restrict__ Gv, const float* __restrict__ Gh,
    unsigned short* __restrict__ ov, unsigned short* __restrict__ oh)
{
    __shared__ float Hb[256];

    const int id   = blockIdx.x;
    const int j    = threadIdx.x & 255;
    const int half = threadIdx.x >> 8;    // wave-uniform
    const bool vert = (id < Bdim * Cdim);

    float L = 0.f, P = 1.f;

    if (vert) {
        int bc = id, b = bc >> 7;
        size_t base = (size_t)bc * SS + j;
        const float* Gb = Gv + (b << 16) + j;
        if (half == 0) {
            float h = 0.f;
            #pragma unroll 8
            for (int i = 0; i < 128; ++i) {
                size_t idx = base + ((size_t)i << 8);
                float g = Gb[i << 8];
                unsigned q = uv[idx];
                h = fmaf(h, g, bf2f((unsigned short)(q >> 16)));
                ov[idx] = f2bf(h * bf2f((unsigned short)q));
            }
            Hb[j] = h;
        } else {
            #pragma unroll 8
            for (int i = 128; i < 256; ++i) {
                float g = Gb[i << 8];
                unsigned q = uv[base + ((size_t)i << 8)];
                L = fmaf(L, g, bf2f((unsigned short)(q >> 16)));
                P *= g;
            }
        }
    } else {
        int bc = id - Bdim * Cdim, b = bc >> 7;
        size_t rbase = (size_t)bc * SS + (size_t)j * Sdim;
        const float* Gb = Gh + (b << 16) + j;
        if (half == 0) {
            size_t obase = (size_t)bc * SS + j;
            float h = 0.f;
            #pragma unroll
            for (int t4 = 0; t4 < 32; ++t4) {
                uint4v q4 = *reinterpret_cast<const uint4v*>(uv + rbase + t4 * 4);
                #pragma unroll
                for (int k = 0; k < 4; ++k) {
                    int i = t4 * 4 + k;
                    float g = Gb[i << 8];
                    h = fmaf(h, g, bf2f((unsigned short)(q4[k] >> 16)));
                    oh[obase + ((size_t)i << 8)] = f2bf(h * bf2f((unsigned short)q4[k]));
                }
            }
            Hb[j] = h;
        } else {
            #pragma unroll
            for (int t4 = 0; t4 < 32; ++t4) {
                uint4v q4 = *reinterpret_cast<const uint4v*>(uv + rbase + 128 + t4 * 4);
                #pragma unroll
                for (int k = 0; k < 4; ++k) {
                    float g = Gb[(128 + t4 * 4 + k) << 8];
                    L = fmaf(L, g, bf2f((unsigned short)(q4[k] >> 16)));
                    P *= g;
                }
            }
        }
    }

    __syncthreads();

    if (half == 1) {
        if (vert) {
            int bc = id;
            size_t base = (size_t)bc * SS + j;
            const float* Gb = Gv + ((bc >> 7) << 16) + j;
            float h0 = Hb[j];
            float Lr = 0.f, Pr = 1.f;
            #pragma unroll 8
            for (int i = 128; i < 256; ++i) {
                size_t idx = base + ((size_t)i << 8);
                float g = Gb[i << 8];
                unsigned q = uv[idx];                       // L2-warm reread
                Lr = fmaf(Lr, g, bf2f((unsigned short)(q >> 16)));
                Pr *= g;
                float h = fmaf(h0, Pr, Lr);
                ov[idx] = f2bf(h * bf2f((unsigned short)q));
            }
        } else {
            int bc = id - Bdim * Cdim;
            size_t rbase = (size_t)bc * SS + (size_t)j * Sdim;
            size_t obase = (size_t)bc * SS + j;
            const float* Gb = Gh + ((bc >> 7) << 16) + j;
            float h0 = Hb[j];
            float Lr = 0.f, Pr = 1.f;
            #pragma unroll
            for (int t4 = 0; t4 < 32; ++t4) {
                uint4v q4 = *reinterpret_cast<const uint4v*>(uv + rbase + 128 + t4 * 4);
                #pragma unroll
                for (int k = 0; k < 4; ++k) {
                    int i = 128 + t4 * 4 + k;
                    float g = Gb[i << 8];
                    Lr = fmaf(Lr, g, bf2f((unsigned short)(q4[k] >> 16)));
                    Pr *= g;
                    float h = fmaf(h0, Pr, Lr);
                    oh[obase + ((size_t)i << 8)] = f2bf(h * bf2f((unsigned short)q4[k]));
                }
            }
        }
    }
}

// ---------------- K3: merge via MFMA, 64-position tile (round-10/11, ~floor) ----------------
__global__ __launch_bounds__(256, 4) void k_merge_mfma(
    const unsigned short* __restrict__ ov, const unsigned short* __restrict__ oh,
    const unsigned short* __restrict__ wm_frag,
    const float* __restrict__ b_merge, float* __restrict__ out)
{
    __shared__ unsigned short lds[16384];   // 32 KB: 64 pos x 256 c
    const int t   = threadIdx.x;
    const int p0  = blockIdx.x * 64;
    const int b   = p0 >> 16;
    const int hw0 = p0 & (SS - 1);

    {
        const int w0 = (t & 7) * 8;
        #pragma unroll
        for (int pass = 0; pass < 8; ++pass) {
            int c = (t >> 3) + pass * 32;
            const unsigned short* src = (c < Cdim)
                ? ov + (((size_t)(b * Cdim + c)) << 16) + hw0 + w0
                : oh + (((size_t)(b * Cdim + (c - Cdim))) << 16) + hw0 + w0;
            ushort8v val = *reinterpret_cast<const ushort8v*>(src);
            int off = ((w0 >> 4) << 12) + ((c >> 2) << 6) + ((c & 3) << 4) + (w0 & 15);
            *reinterpret_cast<ushort8v*>(&lds[off]) = val;
        }
    }
    __syncthreads();

    const int lane = t & 63;
    const int wave = t >> 6;
    const unsigned v_addr = lds_addr_of(lds)
        + (unsigned)((wave << 13) + ((lane >> 4) << 7) + ((lane & 15) << 3));

    float4v acc[8];
    #pragma unroll
    for (int mt = 0; mt < 8; ++mt) acc[mt] = (float4v){0.f, 0.f, 0.f, 0.f};

    const short8v* wf = reinterpret_cast<const short8v*>(wm_frag);

    #pragma unroll 2
    for (int ks2 = 0; ks2 < 4; ++ks2) {
        int ksA = 2 * ks2, ksB = 2 * ks2 + 1;
        unsigned ka = v_addr + (unsigned)(ks2 << 11);
        unsigned long long b00, b01, b10, b11;
        asm volatile(
            "ds_read_b64_tr_b16 %0, %4 offset:0\n\t"
            "ds_read_b64_tr_b16 %1, %4 offset:512\n\t"
            "ds_read_b64_tr_b16 %2, %4 offset:1024\n\t"
            "ds_read_b64_tr_b16 %3, %4 offset:1536\n\t"
            "s_waitcnt lgkmcnt(0)"
            : "=&v"(b00), "=&v"(b01), "=&v"(b10), "=&v"(b11)
            : "v"(ka));
        __builtin_amdgcn_sched_barrier(0);

        union { unsigned long long u[2]; short8v v; } f0, f1;
        f0.u[0] = b00; f0.u[1] = b01;
        f1.u[0] = b10; f1.u[1] = b11;
        short8v bnA = f0.v;
        short8v bnB = f1.v;

        #pragma unroll
        for (int mt = 0; mt < 8; ++mt)
            acc[mt] = __builtin_amdgcn_mfma_f32_16x16x32_bf16(wf[((ksA << 3) + mt) * 64 + lane], bnA, acc[mt], 0, 0, 0);
        #pragma unroll
        for (int mt = 0; mt < 8; ++mt)
            acc[mt] = __builtin_amdgcn_mfma_f32_16x16x32_bf16(wf[((ksB << 3) + mt) * 64 + lane], bnB, acc[mt], 0, 0, 0);
    }

    const int pl = (wave << 4) + (lane & 15);
    const int r0 = (lane >> 4) << 2;
    #pragma unroll
    for (int mt = 0; mt < 8; ++mt) {
        size_t col = (size_t)hw0 + pl;
        #pragma unroll
        for (int r = 0; r < 4; ++r) {
            int co = (mt << 4) + r0 + r;
            out[(((size_t)(b * Cdim + co)) << 16) + col] = acc[mt][r] + b_merge[co];
        }
    }
}

extern "C" void kernel_launch(void* const* d_in, const int* in_sizes, int n_in,
                              void* d_out, int out_size, void* d_ws, size_t ws_size,
                              hipStream_t stream)
{
    const float* x        = (const float*)d_in[0];
    const float* w_reduce = (const float*)d_in[1];
    const float* b_red    = (const float*)d_in[2];
    const float* w_u      = (const float*)d_in[3];
    const float* b_u      = (const float*)d_in[4];
    const float* w_lam    = (const float*)d_in[5];
    const float* b_lam    = (const float*)d_in[6];
    const float* w_w      = (const float*)d_in[7];
    const float* b_w      = (const float*)d_in[8];
    const float* w_merge  = (const float*)d_in[11];
    const float* b_merge  = (const float*)d_in[12];
    float* out = (float*)d_out;

    char* ws = (char*)d_ws;
    unsigned* uv_buf      = (unsigned*)(ws);                       // 64 MiB packed u|v
    unsigned short* ov    = (unsigned short*)(ws + 67108864);      // 32 MiB
    unsigned short* oh    = (unsigned short*)(ws + 100663296);     // 32 MiB
    float* Gv    = (float*)(ws + 134217728);                       // 512 KiB
    float* Gh    = (float*)(ws + 134742016);                       // 512 KiB
    unsigned short* wm_frag = (unsigned short*)(ws + 135282688);   // 64 KiB bf16

    // front-end frags in the (dead until scan) ov region
    unsigned short* wpreA  = (unsigned short*)(ws + 67108864);           // 4 KiB
    unsigned short* wuA2   = (unsigned short*)(ws + 67108864 + 4096);    // 32 KiB
    unsigned short* wlamA2 = (unsigned short*)(ws + 67108864 + 36864);   // 32 KiB
    float* biasPre         = (float*)(ws + 67108864 + 69632);            // 1 KiB
    float* buFrag          = (float*)(ws + 67108864 + 73728);            // 8 KiB
    float* blamFrag        = (float*)(ws + 67108864 + 81920);            // 8 KiB

    hipLaunchKernelGGL(k_prep, dim3(64), dim3(256), 0, stream,
                       w_reduce, w_u, w_lam, w_w, b_red, b_u, b_lam, b_w, w_merge,
                       wm_frag, wpreA, wuA2, wlamA2, biasPre, buFrag, blamFrag);
    hipLaunchKernelGGL(k_front, dim3(NPOS / 128), dim3(256), 0, stream,
                       x, wpreA, biasPre, wuA2, wlamA2, buFrag, blamFrag,
                       uv_buf, Gv, Gh);
    hipLaunchKernelGGL(k_scan_split, dim3(2 * Bdim * Cdim), dim3(512), 0, stream,
                       uv_buf, Gv, Gh, ov, oh);
    hipLaunchKernelGGL(k_merge_mfma, dim3(NPOS / 64), dim3(256), 0, stream,
                       ov, oh, wm_frag, b_merge, out);
}